// Round 2
// baseline (265.618 us; speedup 1.0000x reference)
//
#include <hip/hip_runtime.h>

#define B 8
#define N 8192
#define M 2048
#define NITER 4
#define BASE_ALPHA 0.1f
#define MARGIN 0.02f           // covers fp slack (~1e-4) on the NN-invariance bound
#define CAP 30                 // candidate-list capacity (expected count ~2-3)

#define NTHR 1024              // 16 waves
#define NPT 32                 // point-lanes per split
#define NSPLIT 32              // j-splits per block
#define JS (M / NSPLIT)        // 64 y's per split
#define JQ (JS / 4)            // 16 j-quads per split
#define PT 8                   // points per thread
#define PPB (NPT * PT)         // 256 points per block
#define NBLK (B * N / PPB)     // 256 blocks (iter0)
#define BPB (NBLK / B)         // 32 blocks per batch

// ws layout: pos4 float4[B*N] @0 (1MB); aux uint2[B*N] @1MB (bits(md), logical
// nearest idx); cand uint4[B*N][4] @1.5MB (4MB): word0=count (0xFFFFFFFF =
// overflow -> tail full-scans), words 1..15 = up to 30 uint16 candidate j's,
// ascending. NN-invariance: the computed argmin at iters 1-3 lies in
// {j : dist_0(j) <= d_0 + MARGIN} (telescoping movement bound, robust to
// fp argmin flips since sum of alpha_i*md_i*prod(1-alpha_j) telescopes).
#define OFF_AUX   (1024 * 1024)
#define OFF_CAND  (1536 * 1024)

typedef float f2 __attribute__((ext_vector_type(2)));

// ---------------- iter 0: full scan + candidate-list emission ----------------
__global__ __launch_bounds__(NTHR, 4) void iter_kernel(const float* __restrict__ pred,
                                                       const float* __restrict__ partial,
                                                       float4* __restrict__ pos4,
                                                       uint2* __restrict__ aux,
                                                       uint4* __restrict__ cand) {
    __shared__ float4 sX[M / 4], sY[M / 4], sZ[M / 4], sW[M / 4];  // 32 KB
    __shared__ float smint[NSPLIT][PPB];                           // 32 KB
    __shared__ float4 lpos[PPB];
    __shared__ unsigned short cc[PPB][32];                         // 16 KB cand lists
    __shared__ unsigned int ccnt[PPB];

    const int tid = threadIdx.x;
    const int b = blockIdx.x >> 5;
    const int blk = blockIdx.x & 31;
    const int gp0 = b * N + blk * PPB;

    // Build SoA tile. (-2y)*x bit-equal to reference's (-2x)*y.
    const float* pa = partial + b * M * 3;
    if (tid < M / 4) {
        int sp = tid & 31, jq = tid >> 5;
        const float* p0 = pa + (sp * JS + jq * 4) * 3;
        float a0 = p0[0], a1 = p0[1],  a2 = p0[2];
        float b0 = p0[3], b1 = p0[4],  b2 = p0[5];
        float c0 = p0[6], c1 = p0[7],  c2 = p0[8];
        float d0 = p0[9], d1 = p0[10], d2 = p0[11];
        sX[tid] = make_float4(-2.f * a0, -2.f * b0, -2.f * c0, -2.f * d0);
        sY[tid] = make_float4(-2.f * a1, -2.f * b1, -2.f * c1, -2.f * d1);
        sZ[tid] = make_float4(-2.f * a2, -2.f * b2, -2.f * c2, -2.f * d2);
        sW[tid] = make_float4(a0 * a0 + a1 * a1 + a2 * a2, b0 * b0 + b1 * b1 + b2 * b2,
                              c0 * c0 + c1 * c1 + c2 * c2, d0 * d0 + d1 * d1 + d2 * d2);
    }

    // Owners: refined_0 = pred.
    if (tid < PPB) {
        const int p = gp0 + tid;
        const float* pp = pred + (unsigned long long)p * 3;
        float rx = pp[0], ry = pp[1], rz = pp[2];
        float w = rx * rx + ry * ry + rz * rz;
        lpos[tid] = make_float4(rx, ry, rz, w);
        pos4[p] = make_float4(rx, ry, rz, w);
    }
    __syncthreads();

    const int split = tid >> 5;                    // 0..31 (uniform per half-wave)
    const int pt = tid & 31;

    // ---- pass 1: packed-f32 per-split min ----
    f2 sx[PT], sy[PT], sz[PT];
    #pragma unroll
    for (int k = 0; k < PT; ++k) {
        float4 r = lpos[pt + k * NPT];
        sx[k] = (f2){r.x, r.x}; sy[k] = (f2){r.y, r.y}; sz[k] = (f2){r.z, r.z};
    }
    f2 acc[PT];
    #pragma unroll
    for (int k = 0; k < PT; ++k) acc[k] = (f2){3.402823466e+38f, 3.402823466e+38f};

    #pragma unroll 2
    for (int jq = 0; jq < JQ; ++jq) {
        float4 qx = sX[jq * 32 + split], qy = sY[jq * 32 + split];
        float4 qz = sZ[jq * 32 + split], qw = sW[jq * 32 + split];
        f2 qx01 = (f2){qx.x, qx.y}, qx23 = (f2){qx.z, qx.w};
        f2 qy01 = (f2){qy.x, qy.y}, qy23 = (f2){qy.z, qy.w};
        f2 qz01 = (f2){qz.x, qz.y}, qz23 = (f2){qz.z, qz.w};
        f2 qw01 = (f2){qw.x, qw.y}, qw23 = (f2){qw.z, qw.w};
        #pragma unroll
        for (int k = 0; k < PT; ++k) {
            f2 t01 = __builtin_elementwise_fma(sx[k], qx01,
                     __builtin_elementwise_fma(sy[k], qy01,
                     __builtin_elementwise_fma(sz[k], qz01, qw01)));
            f2 t23 = __builtin_elementwise_fma(sx[k], qx23,
                     __builtin_elementwise_fma(sy[k], qy23,
                     __builtin_elementwise_fma(sz[k], qz23, qw23)));
            acc[k] = __builtin_elementwise_min(acc[k],
                     __builtin_elementwise_min(t01, t23));     // exact, order-invariant
        }
    }
    #pragma unroll
    for (int k = 0; k < PT; ++k)
        smint[split][pt + k * NPT] = fminf(acc[k].x, acc[k].y);
    __syncthreads();

    // ---- owners: md from split minima; candidate scan over masked splits ----
    if (tid < PPB) {
        float tstar = 3.402823466e+38f;
        #pragma unroll
        for (int s = 0; s < NSPLIT; ++s) tstar = fminf(tstar, smint[s][tid]);
        const float4 f4 = lpos[tid];
        const float md = sqrtf(fmaxf(f4.w + tstar, 0.0f));

        // threshold: dist <= md + MARGIN  <=>  t <= (md+MARGIN)^2 - w
        float mdm = md + MARGIN;
        float thr = fmaf(mdm, mdm, -f4.w);

        // Ascending-j scan of qualifying splits: strict < keeps first-argmin;
        // every min-achieving j satisfies t <= thr, so argmin over the union
        // equals the global first-argmin. Collect candidates (t <= thr).
        float bt = 3.402823466e+38f; int bj = 0;
        int cnt = 0;
        for (int s = 0; s < NSPLIT; ++s) {
            if (smint[s][tid] > thr) continue;
            for (int jq = 0; jq < JQ; ++jq) {
                float4 qx = sX[jq * 32 + s], qy = sY[jq * 32 + s];
                float4 qz = sZ[jq * 32 + s], qw = sW[jq * 32 + s];
                float t0 = fmaf(f4.x, qx.x, fmaf(f4.y, qy.x, fmaf(f4.z, qz.x, qw.x)));
                float t1 = fmaf(f4.x, qx.y, fmaf(f4.y, qy.y, fmaf(f4.z, qz.y, qw.y)));
                float t2 = fmaf(f4.x, qx.z, fmaf(f4.y, qy.z, fmaf(f4.z, qz.z, qw.z)));
                float t3 = fmaf(f4.x, qx.w, fmaf(f4.y, qy.w, fmaf(f4.z, qz.w, qw.w)));
                int j0 = s * JS + jq * 4;
                if (t0 < bt) { bt = t0; bj = j0 + 0; }
                if (t1 < bt) { bt = t1; bj = j0 + 1; }
                if (t2 < bt) { bt = t2; bj = j0 + 2; }
                if (t3 < bt) { bt = t3; bj = j0 + 3; }
                if (t0 <= thr) { if (cnt < CAP) cc[tid][cnt] = (unsigned short)(j0 + 0); ++cnt; }
                if (t1 <= thr) { if (cnt < CAP) cc[tid][cnt] = (unsigned short)(j0 + 1); ++cnt; }
                if (t2 <= thr) { if (cnt < CAP) cc[tid][cnt] = (unsigned short)(j0 + 2); ++cnt; }
                if (t3 <= thr) { if (cnt < CAP) cc[tid][cnt] = (unsigned short)(j0 + 3); ++cnt; }
            }
        }
        ccnt[tid] = (cnt > CAP) ? 0xFFFFFFFFu : (unsigned int)cnt;
        aux[gp0 + tid] = make_uint2(__float_as_uint(md), (unsigned int)bj);
    }
    __syncthreads();

    // Cooperative coalesced copy of candidate records (uint4 per thread).
    {
        int p = tid >> 2, q = tid & 3;
        const unsigned short* row = cc[p];
        unsigned int w0, w1, w2, w3;
        if (q == 0) {
            w0 = ccnt[p];
            w1 = (unsigned int)row[0] | ((unsigned int)row[1] << 16);
            w2 = (unsigned int)row[2] | ((unsigned int)row[3] << 16);
            w3 = (unsigned int)row[4] | ((unsigned int)row[5] << 16);
        } else {
            int h0 = q * 8 - 2;
            w0 = (unsigned int)row[h0 + 0] | ((unsigned int)row[h0 + 1] << 16);
            w1 = (unsigned int)row[h0 + 2] | ((unsigned int)row[h0 + 3] << 16);
            w2 = (unsigned int)row[h0 + 4] | ((unsigned int)row[h0 + 5] << 16);
            w3 = (unsigned int)row[h0 + 6] | ((unsigned int)row[h0 + 7] << 16);
        }
        cand[(unsigned long long)gp0 * 4 + tid] = make_uint4(w0, w1, w2, w3);
    }
}

// ---------------- iters 1..3 + final, one block per batch ----------------
// Batch max is block-local (8192 pts = 1024 thr x 8). State in registers;
// y-tile staged once. All arithmetic chains verbatim from iter/light/final.
__global__ __launch_bounds__(NTHR, 4) void tail_kernel(const float* __restrict__ partial,
                                                       const float4* __restrict__ pos4,
                                                       const uint2* __restrict__ aux,
                                                       const uint4* __restrict__ cand,
                                                       float* __restrict__ out) {
    __shared__ float4 sQ[M];       // (-2y0,-2y1,-2y2,|y|^2)  32 KB
    __shared__ float redw[16];
    __shared__ float mxsh;

    const int tid = threadIdx.x;
    const int b = blockIdx.x;

    const float* pa = partial + b * M * 3;
    for (int j = tid; j < M; j += NTHR) {
        float a0 = pa[j * 3 + 0], a1 = pa[j * 3 + 1], a2 = pa[j * 3 + 2];
        sQ[j] = make_float4(-2.f * a0, -2.f * a1, -2.f * a2,
                            a0 * a0 + a1 * a1 + a2 * a2);
    }

    float rx[8], ry[8], rz[8], md[8];
    int idx[8];
    unsigned int cnt[8];
    #pragma unroll
    for (int k = 0; k < 8; ++k) {
        int p = b * N + k * NTHR + tid;
        float4 f = pos4[p];
        uint2 a = aux[p];
        rx[k] = f.x; ry[k] = f.y; rz[k] = f.z;
        md[k] = __uint_as_float(a.x);
        idx[k] = (int)a.y;
        cnt[k] = cand[(unsigned long long)p * 4].x;
    }
    __syncthreads();

    for (int it = 1; it < NITER; ++it) {
        // batch max of md (exact: fmax is order-invariant)
        float vm = md[0];
        #pragma unroll
        for (int k = 1; k < 8; ++k) vm = fmaxf(vm, md[k]);
        #pragma unroll
        for (int o = 32; o > 0; o >>= 1) vm = fmaxf(vm, __shfl_xor(vm, o));
        if ((tid & 63) == 0) redw[tid >> 6] = vm;
        __syncthreads();
        if (tid == 0) {
            float v = redw[0];
            #pragma unroll
            for (int r = 1; r < 16; ++r) v = fmaxf(v, redw[r]);
            mxsh = v;
        }
        __syncthreads();

        float inv = 1.0f / (mxsh + 1e-6f);
        #pragma unroll
        for (int k = 0; k < 8; ++k) {
            int p = b * N + k * NTHR + tid;
            float4 q = sQ[idx[k]];
            float ny0 = -0.5f * q.x;               // exact y bits
            float ny1 = -0.5f * q.y;
            float ny2 = -0.5f * q.z;
            float alpha = BASE_ALPHA * (2.0f - md[k] * inv);
            float nx = fmaf(alpha, ny0 - rx[k], rx[k]);
            float nyv = fmaf(alpha, ny1 - ry[k], ry[k]);
            float nz = fmaf(alpha, ny2 - rz[k], rz[k]);
            rx[k] = nx; ry[k] = nyv; rz[k] = nz;
            float w = nx * nx + nyv * nyv + nz * nz;

            float bt = 3.402823466e+38f; int bj = 0;
            unsigned int c0 = cnt[k];
            if (c0 <= CAP) {
                const unsigned short* cp = (const unsigned short*)(cand + (unsigned long long)p * 4) + 2;
                for (unsigned int c = 0; c < c0; ++c) {
                    int j = cp[c];
                    float4 qq = sQ[j];
                    float t = fmaf(nx, qq.x, fmaf(nyv, qq.y, fmaf(nz, qq.z, qq.w)));
                    if (t < bt) { bt = t; bj = j; }     // ascending j, strict < = first-argmin
                }
            } else {                                    // overflow fallback: exact full scan
                for (int j = 0; j < M; ++j) {
                    float4 qq = sQ[j];
                    float t = fmaf(nx, qq.x, fmaf(nyv, qq.y, fmaf(nz, qq.z, qq.w)));
                    if (t < bt) { bt = t; bj = j; }
                }
            }
            md[k] = sqrtf(fmaxf(w + bt, 0.0f));
            idx[k] = bj;
        }
        __syncthreads();   // protect redw/mxsh reuse next iteration
    }

    // final output (verbatim final_kernel chain; -0.5*(-2y) == raw y bits)
    {
        float vm = md[0];
        #pragma unroll
        for (int k = 1; k < 8; ++k) vm = fmaxf(vm, md[k]);
        #pragma unroll
        for (int o = 32; o > 0; o >>= 1) vm = fmaxf(vm, __shfl_xor(vm, o));
        if ((tid & 63) == 0) redw[tid >> 6] = vm;
        __syncthreads();
        if (tid == 0) {
            float v = redw[0];
            #pragma unroll
            for (int r = 1; r < 16; ++r) v = fmaxf(v, redw[r]);
            mxsh = v;
        }
        __syncthreads();

        float inv = 1.0f / (mxsh + 1e-6f);
        #pragma unroll
        for (int k = 0; k < 8; ++k) {
            int p = b * N + k * NTHR + tid;
            float4 q = sQ[idx[k]];
            float y0 = -0.5f * q.x, y1 = -0.5f * q.y, y2 = -0.5f * q.z;
            float alpha = BASE_ALPHA * (2.0f - md[k] * inv);
            float* po = out + (unsigned long long)p * 3;
            po[0] = fmaf(alpha, y0 - rx[k], rx[k]);
            po[1] = fmaf(alpha, y1 - ry[k], ry[k]);
            po[2] = fmaf(alpha, y2 - rz[k], rz[k]);
        }
    }
}

extern "C" void kernel_launch(void* const* d_in, const int* in_sizes, int n_in,
                              void* d_out, int out_size, void* d_ws, size_t ws_size,
                              hipStream_t stream) {
    const float* pred = (const float*)d_in[0];
    const float* partial = (const float*)d_in[1];
    char* ws = (char*)d_ws;
    float4* pos4 = (float4*)ws;
    uint2* aux = (uint2*)(ws + OFF_AUX);
    uint4* candb = (uint4*)(ws + OFF_CAND);
    float* out = (float*)d_out;

    hipLaunchKernelGGL(iter_kernel, dim3(NBLK), dim3(NTHR), 0, stream,
                       pred, partial, pos4, aux, candb);
    hipLaunchKernelGGL(tail_kernel, dim3(B), dim3(NTHR), 0, stream,
                       partial, pos4, aux, candb, out);
}